// Round 10
// baseline (122.671 us; speedup 1.0000x reference)
//
#include <hip/hip_runtime.h>
#include <stdint.h>
#include <stddef.h>

// Problem constants (match reference setup_inputs)
static constexpr int Bb = 2;      // batch
static constexpr int Mq = 4096;   // queries per batch
static constexpr int Cc = 256;    // channels (GEMM K)
static constexpr int Hh = 64, Ww = 64;
static constexpr int Np = Hh * Ww;     // 4096 pixels (GEMM N)
static constexpr int RAD = 4;
static constexpr int SIDE = 2 * RAD + 1;     // 9
static constexpr int KPL = SIDE * SIDE;      // 81
static constexpr int NLVL = 4;
static constexpr int KTOT = NLVL * KPL;      // 324

// Workspace layout (bytes)
static constexpr size_t L1BUF_B  = 0;                                    // 16.8 MB bf16
static constexpr size_t WINBUF_B = (size_t)Bb * Mq * 1024 * 2;           // +3.3 MB fp32
static constexpr size_t ABF_B    = WINBUF_B + (size_t)Bb * Mq * 100 * 4; // +4.2 MB bf16
static constexpr size_t BT_B     = ABF_B + (size_t)Bb * Mq * Cc * 2;     // +4.2 MB bf16

typedef float floatx4 __attribute__((ext_vector_type(4)));
typedef short shortx8 __attribute__((ext_vector_type(8)));

union BfPack {
    shortx8 v;
    unsigned short u[8];
};

// fp32 -> bf16 round-to-nearest-even (finite inputs only)
__device__ __forceinline__ unsigned short f2bf(float f) {
    unsigned int x = __float_as_uint(f);
    x += 0x7fffu + ((x >> 16) & 1u);
    return (unsigned short)(x >> 16);
}

__device__ __forceinline__ float bf2f(unsigned short u) {
    return __uint_as_float((unsigned int)u << 16);
}

// async global->LDS, 16 B per lane; LDS dest = base + lane*16 (wave-uniform base)
__device__ __forceinline__ void gll16(const void* g, void* l) {
    __builtin_amdgcn_global_load_lds(
        (const __attribute__((address_space(1))) unsigned int*)g,
        (__attribute__((address_space(3))) unsigned int*)l, 16, 0, 0);
}

// ---------------------------------------------------------------------------
// Merged prep: blocks [0,1024) convert fmap1 fp32->bf16 (same layout);
// blocks [1024,1536) transpose fmap2 (b,c,p) -> Bt (b,p,c) bf16 via LDS tile.
// ---------------------------------------------------------------------------
__global__ __launch_bounds__(256)
void cvt_kernel(const float* __restrict__ f1, const float* __restrict__ f2,
                unsigned short* __restrict__ Abf, unsigned short* __restrict__ Bt)
{
    __shared__ float tile[64 * 65];
    const int tid = threadIdx.x;
    if (blockIdx.x < 1024) {
        const int t = blockIdx.x * 256 + tid;      // 262144 threads x 8 elems
        const float4 v0 = *(const float4*)(f1 + (size_t)t * 8);
        const float4 v1 = *(const float4*)(f1 + (size_t)t * 8 + 4);
        BfPack p;
        p.u[0] = f2bf(v0.x); p.u[1] = f2bf(v0.y);
        p.u[2] = f2bf(v0.z); p.u[3] = f2bf(v0.w);
        p.u[4] = f2bf(v1.x); p.u[5] = f2bf(v1.y);
        p.u[6] = f2bf(v1.z); p.u[7] = f2bf(v1.w);
        *(shortx8*)(Abf + (size_t)t * 8) = p.v;
        return;
    }
    const int bid = blockIdx.x - 1024;             // 512 transpose blocks
    const int p0 = (bid & 63) * 64;
    const int c0 = ((bid >> 6) & 3) * 64;
    const int b  = bid >> 8;

    // load: coalesced along p
    const int pl = tid & 63;
    const int cb = tid >> 6;     // 0..3
#pragma unroll
    for (int it = 0; it < 16; ++it) {
        const int cl = it * 4 + cb;
        tile[cl * 65 + pl] = f2[((size_t)(b * Cc + c0 + cl)) * Np + p0 + pl];
    }
    __syncthreads();

    // store: coalesced along c (8 bf16 = 16 B per thread-write)
    const int cg = (tid & 7) * 8;
#pragma unroll
    for (int it = 0; it < 2; ++it) {
        const int pw = it * 32 + (tid >> 3);
        BfPack p;
#pragma unroll
        for (int u = 0; u < 8; ++u)
            p.u[u] = f2bf(tile[(cg + u) * 65 + pw]);
        *(shortx8*)(Bt + ((size_t)(b * Np + p0 + pw)) * Cc + c0 + cg) = p.v;
    }
}

// ---------------------------------------------------------------------------
// Fused correlation GEMM + level-1 pooling + level-0 window extraction.
// R9 structure (dbuf global_load_lds + source-side XOR bank swizzle), plus:
//  - LDS trimmed to exactly 32 KB (qx0/qy0 computed in epilogue from cent)
//    -> 5 blocks/CU occupancy (was 4).
//  - K-loop unrolled x2 with explicit buffer names (no (k0&1) indexing,
//    all prefetch predicates static).
// 128x128 tile, 4 waves, 4x4 16x16x32 bf16 tiles/wave, 8 K-iters.
// ---------------------------------------------------------------------------
__global__ __launch_bounds__(256)
void corr_gemm_pool_kernel(const unsigned short* __restrict__ Abf, // (Bb*Mq, Cc)
                           const unsigned short* __restrict__ Bt,  // (Bb*Np, Cc)
                           const float* __restrict__ cent,         // (Bb*Mq, 2)
                           unsigned short* __restrict__ l1buf,     // (Bb*Mq, 1024) bf16
                           float* __restrict__ winbuf)             // (Bb*Mq, 100)
{
    __shared__ union {
        unsigned short stage[2][2][128 * 32]; // [buf][a=0/b=1][row*32+k] 32 KB
        float corrT[32 * 131];                // epilogue staging (16.8 KB)
    } sm;

    const int b    = blockIdx.z;
    const int bm0  = blockIdx.y * 128;
    const int bx   = blockIdx.x;             // image row pair {2bx, 2bx+1}
    const int bn0  = bx * 128;
    const int tid  = threadIdx.x;
    const int lane = tid & 63;
    const int wave = tid >> 6;
    const int lane15 = lane & 15;
    const int quad   = lane >> 4;
    const int wm = (wave >> 1) * 64;
    const int wn = (wave & 1) * 64;

    // staging addresses: one instr covers 16 rows; lane -> row lane/4,
    // SWIZZLED k-group (lane&3)^((row>>1)&3) so slot (r,g) = global (r,g^sig)
    const int lrow = lane >> 2;
    const int lkg  = (((lane & 3) ^ ((lrow >> 1) & 3))) * 8;
    const unsigned short* aptr = Abf + (size_t)(b * Mq + bm0 + wave * 16 + lrow) * Cc + lkg;
    const unsigned short* bptr = Bt  + (size_t)(b * Np + bn0 + wave * 16 + lrow) * Cc + lkg;

    floatx4 acc[4][4];
#pragma unroll
    for (int i = 0; i < 4; ++i)
#pragma unroll
        for (int j = 0; j < 4; ++j)
            acc[i][j] = floatx4{0.0f, 0.0f, 0.0f, 0.0f};

    unsigned short* a0 = sm.stage[0][0];
    unsigned short* b0 = sm.stage[0][1];
    unsigned short* a1 = sm.stage[1][0];
    unsigned short* b1 = sm.stage[1][1];

    // prologue: stage k-tile 0 into buffer 0
    gll16(aptr,           &a0[wave * 512]);
    gll16(aptr + 64 * Cc, &a0[2048 + wave * 512]);
    gll16(bptr,           &b0[wave * 512]);
    gll16(bptr + 64 * Cc, &b0[2048 + wave * 512]);

    // reader-side swizzled k-group offset (row within 16-seg == lane15)
    const int rq = (quad ^ ((lane15 >> 1) & 3)) * 8;

#pragma unroll
    for (int kk = 0; kk < 4; ++kk) {
        const int ke = 2 * kk;        // even tile index (compile-time)
        // ---- even iter: compute buf0, prefetch tile ke+1 -> buf1
        __syncthreads();
        {
            const int ko = (ke + 1) * 32;
            gll16(aptr + ko,           &a1[wave * 512]);
            gll16(aptr + 64 * Cc + ko, &a1[2048 + wave * 512]);
            gll16(bptr + ko,           &b1[wave * 512]);
            gll16(bptr + 64 * Cc + ko, &b1[2048 + wave * 512]);
        }
        {
            shortx8 af[4], bf[4];
#pragma unroll
            for (int i = 0; i < 4; ++i)
                af[i] = *(const shortx8*)&a0[(wm + i * 16 + lane15) * 32 + rq];
#pragma unroll
            for (int j = 0; j < 4; ++j)
                bf[j] = *(const shortx8*)&b0[(wn + j * 16 + lane15) * 32 + rq];
#pragma unroll
            for (int i = 0; i < 4; ++i)
#pragma unroll
                for (int j = 0; j < 4; ++j)
                    acc[i][j] = __builtin_amdgcn_mfma_f32_16x16x32_bf16(
                        af[i], bf[j], acc[i][j], 0, 0, 0);
        }
        // ---- odd iter: compute buf1, prefetch tile ke+2 -> buf0
        __syncthreads();
        if (kk < 3) {
            const int ko = (ke + 2) * 32;
            gll16(aptr + ko,           &a0[wave * 512]);
            gll16(aptr + 64 * Cc + ko, &a0[2048 + wave * 512]);
            gll16(bptr + ko,           &b0[wave * 512]);
            gll16(bptr + 64 * Cc + ko, &b0[2048 + wave * 512]);
        }
        {
            shortx8 af[4], bf[4];
#pragma unroll
            for (int i = 0; i < 4; ++i)
                af[i] = *(const shortx8*)&a1[(wm + i * 16 + lane15) * 32 + rq];
#pragma unroll
            for (int j = 0; j < 4; ++j)
                bf[j] = *(const shortx8*)&b1[(wn + j * 16 + lane15) * 32 + rq];
#pragma unroll
            for (int i = 0; i < 4; ++i)
#pragma unroll
                for (int j = 0; j < 4; ++j)
                    acc[i][j] = __builtin_amdgcn_mfma_f32_16x16x32_bf16(
                        af[i], bf[j], acc[i][j], 0, 0, 0);
        }
    }

    // ---- epilogue: 4 chunks of 32 queries through LDS; pool + window ----
    // C/D layout: col = lane15, row = quad*4+reg (m89/m91 verified).
    float* corrT = sm.corrT;
    const int m_local = tid >> 3;   // 0..31 (query within chunk)
    const int xi      = tid & 7;
#pragma unroll
    for (int c = 0; c < 4; ++c) {
        __syncthreads();
        if ((wave >> 1) == (c >> 1)) {
#pragma unroll
            for (int ii = 0; ii < 2; ++ii) {
                const int i = 2 * (c & 1) + ii;
#pragma unroll
                for (int j = 0; j < 4; ++j) {
#pragma unroll
                    for (int reg = 0; reg < 4; ++reg) {
                        const int rl = ii * 16 + quad * 4 + reg;
                        const int n  = wn + j * 16 + lane15;
                        corrT[rl * 131 + n] = acc[i][j][reg];
                    }
                }
            }
        }
        __syncthreads();

        const int mg = 32 * c + m_local;            // block-local query
        const size_t gq = (size_t)(b * Mq + bm0 + mg);
        const float* T = &corrT[m_local * 131];

        // 2x2 pool -> one L1 row (32 bf16 values) per query
#pragma unroll
        for (int k = 0; k < 4; ++k) {
            const int c1 = xi + 8 * k;
            const float v = 0.25f * (T[2 * c1] + T[2 * c1 + 1]
                                   + T[64 + 2 * c1] + T[64 + 2 * c1 + 1]);
            l1buf[gq * 1024 + bx * 32 + c1] = f2bf(v);
        }

        // level-0 window rows intersecting [qy0, qy0+9] (fp32, exact)
        // window origin from cent directly (8B broadcast per 8-thread group)
        const int x0w = (int)floorf(cent[gq * 2 + 0]) - RAD;
        const int y0w = (int)floorf(cent[gq * 2 + 1]) - RAD;
#pragma unroll
        for (int par = 0; par < 2; ++par) {
            const int wy = 2 * bx + par - y0w;
            if (wy >= 0 && wy < 10) {
#pragma unroll
                for (int t = 0; t < 2; ++t) {
                    const int wx = xi + t * 8;
                    if (wx < 10) {
                        const int x = x0w + wx;
                        if (x >= 0 && x < Ww)
                            winbuf[gq * 100 + wy * 10 + wx] = T[par * 64 + x];
                    }
                }
            }
        }
    }
}

// ---------------------------------------------------------------------------
// Sampler: 8 queries/block. Loads L1 (2 KB bf16/query) + window (400 B/query),
// builds L2/L3 in LDS, emits all 324 outputs per query.
// ---------------------------------------------------------------------------
__global__ __launch_bounds__(256)
void pyr_sample_kernel(const float* __restrict__ cent,           // (Bb*Mq, 2)
                       const unsigned short* __restrict__ l1buf, // (Bb*Mq, 1024) bf16
                       const float* __restrict__ winbuf,         // (Bb*Mq, 100)
                       float* __restrict__ out)                  // (Bb, 324, Mq)
{
    __shared__ float l1[8][1024];    // 32x32
    __shared__ float l2[8][256];     // 16x16
    __shared__ float l3[8][64];      // 8x8
    __shared__ float win0[8][100];   // 10x10 L0 window
    __shared__ float qcx[8], qcy[8];
    __shared__ int   qx0[8], qy0[8];

    const int tid = threadIdx.x;
    const int b   = blockIdx.x >> 9;           // 512 blocks per batch
    const int m0  = (blockIdx.x & 511) * 8;
    const size_t gq0 = (size_t)(b * Mq + m0);

    if (tid < 8) {
        const float cx = cent[(gq0 + tid) * 2 + 0];
        const float cy = cent[(gq0 + tid) * 2 + 1];
        qcx[tid] = cx; qcy[tid] = cy;
        qx0[tid] = (int)floorf(cx) - RAD;
        qy0[tid] = (int)floorf(cy) - RAD;
    }

    // load L1: 8 queries x 128 ushort8 (16 B) each -> expand bf16 to f32 LDS
#pragma unroll
    for (int it = 0; it < 4; ++it) {
        const int v = it * 256 + tid;          // ushort8 index, 0..1023
        const int q = v >> 7;
        const int o = v & 127;
        BfPack p;
        p.v = *(const shortx8*)&l1buf[(gq0 + q) * 1024 + o * 8];
#pragma unroll
        for (int u = 0; u < 8; ++u)
            l1[q][o * 8 + u] = bf2f(p.u[u]);
    }
    // load windows: 8 queries x 25 float4
    if (tid < 200) {
        const int q = tid / 25;
        const int o = tid - q * 25;
        *(float4*)&win0[q][o * 4] = *(const float4*)&winbuf[(gq0 + q) * 100 + o * 4];
    }
    __syncthreads();

    // L2 from L1
#pragma unroll
    for (int i = 0; i < 8; ++i) {
        const int idx = i * 256 + tid;
        const int q = idx >> 8;
        const int c = idx & 255;
        const int cy2 = c >> 4, cx2 = c & 15;
        const float* s = &l1[q][(2 * cy2) * 32 + 2 * cx2];
        l2[q][c] = 0.25f * (s[0] + s[1] + s[32] + s[33]);
    }
    __syncthreads();
    // L3 from L2
#pragma unroll
    for (int i = 0; i < 2; ++i) {
        const int idx = i * 256 + tid;
        const int q = idx >> 6;
        const int c = idx & 63;
        const int cy3 = c >> 3, cx3 = c & 7;
        const float* s = &l2[q][(2 * cy3) * 16 + 2 * cx3];
        l3[q][c] = 0.25f * (s[0] + s[1] + s[16] + s[17]);
    }
    __syncthreads();

    // sampling: 324*8 = 2592 outputs
    for (int i = 0; i < 11; ++i) {
        const int idx = i * 256 + tid;
        if (idx >= KTOT * 8) break;
        const int q  = idx & 7;
        const int kk = idx >> 3;           // 0..323
        const int lvl = kk / KPL;
        const int r   = kk - lvl * KPL;
        const int di  = r / SIDE;          // x-offset index
        const int dj  = r - di * SIDE;     // y-offset index

        const int w = Ww >> lvl;
        const float scale = 1.0f / (float)(1 << lvl);
        const float x = qcx[q] * scale + (float)(di - RAD);
        const float y = qcy[q] * scale + (float)(dj - RAD);

        const float x0f = floorf(x), y0f = floorf(y);
        const float wx1 = x - x0f, wx0 = 1.0f - wx1;
        const float wy1 = y - y0f, wy0 = 1.0f - wy1;
        const float fmx = (float)(w - 1);
        const bool vx0 = (x0f >= 0.0f) && (x0f <= fmx);
        const bool vx1 = (x0f + 1.0f >= 0.0f) && (x0f + 1.0f <= fmx);
        const bool vy0 = (y0f >= 0.0f) && (y0f <= fmx);
        const bool vy1 = (y0f + 1.0f >= 0.0f) && (y0f + 1.0f <= fmx);

        const int ix0 = (int)x0f, iy0 = (int)y0f;

        const float* buf;
        int stride, ox, oy;
        if (lvl == 0)      { buf = win0[q]; stride = 10; ox = qx0[q]; oy = qy0[q]; }
        else if (lvl == 1) { buf = l1[q];   stride = 32; ox = 0; oy = 0; }
        else if (lvl == 2) { buf = l2[q];   stride = 16; ox = 0; oy = 0; }
        else               { buf = l3[q];   stride =  8; ox = 0; oy = 0; }

        const int cx0 = ix0 - ox, cx1 = ix0 + 1 - ox;
        const int cy0r = iy0 - oy, cy1r = iy0 + 1 - oy;
        const float g00 = (vx0 && vy0) ? buf[cy0r * stride + cx0] : 0.0f;
        const float g10 = (vx1 && vy0) ? buf[cy0r * stride + cx1] : 0.0f;
        const float g01 = (vx0 && vy1) ? buf[cy1r * stride + cx0] : 0.0f;
        const float g11 = (vx1 && vy1) ? buf[cy1r * stride + cx1] : 0.0f;

        out[((size_t)b * KTOT + kk) * Mq + m0 + q] =
            wy0 * (wx0 * g00 + wx1 * g10) + wy1 * (wx0 * g01 + wx1 * g11);
    }
}

extern "C" void kernel_launch(void* const* d_in, const int* in_sizes, int n_in,
                              void* d_out, int out_size, void* d_ws, size_t ws_size,
                              hipStream_t stream)
{
    const float* fmap1 = (const float*)d_in[0];   // (Bb, Mq, Cc)
    const float* fmap2 = (const float*)d_in[1];   // (Bb, Cc, Hh, Ww)
    const float* cent  = (const float*)d_in[2];   // (Bb, Mq, 2)
    char* ws = (char*)d_ws;
    unsigned short* l1buf = (unsigned short*)(ws + L1BUF_B);
    float* winbuf = (float*)(ws + WINBUF_B);
    unsigned short* Abf = (unsigned short*)(ws + ABF_B);
    unsigned short* Bt  = (unsigned short*)(ws + BT_B);
    float* out = (float*)d_out;

    // 0) merged prep: A cvt (1024 blocks) + B transpose/cvt (512 blocks)
    cvt_kernel<<<1536, 256, 0, stream>>>(fmap1, fmap2, Abf, Bt);

    // 1) fused correlation GEMM (dbuf global_load_lds, bank-swizzled LDS,
    //    32 KB LDS -> 5 blocks/CU, unrolled K-loop)
    //    + L1 pooling (bf16 out) + L0 window extraction
    dim3 ggrid(Np / 128, Mq / 128, Bb);
    corr_gemm_pool_kernel<<<ggrid, 256, 0, stream>>>(Abf, Bt, cent, l1buf, winbuf);

    // 2) pyramid completion (L2/L3 in LDS) + bilinear sampling
    const int nblk = Bb * Mq / 8;   // 1024
    pyr_sample_kernel<<<nblk, 256, 0, stream>>>(cent, l1buf, winbuf, out);
}

// Round 11
// 120.314 us; speedup vs baseline: 1.0196x; 1.0196x over previous
//
#include <hip/hip_runtime.h>
#include <stdint.h>
#include <stddef.h>

// Problem constants (match reference setup_inputs)
static constexpr int Bb = 2;      // batch
static constexpr int Mq = 4096;   // queries per batch
static constexpr int Cc = 256;    // channels (GEMM K)
static constexpr int Hh = 64, Ww = 64;
static constexpr int Np = Hh * Ww;     // 4096 pixels (GEMM N)
static constexpr int RAD = 4;
static constexpr int SIDE = 2 * RAD + 1;     // 9
static constexpr int KPL = SIDE * SIDE;      // 81
static constexpr int NLVL = 4;
static constexpr int KTOT = NLVL * KPL;      // 324

// Workspace layout (bytes)
static constexpr size_t L1BUF_B  = 0;                                    // 16.8 MB bf16
static constexpr size_t WINBUF_B = (size_t)Bb * Mq * 1024 * 2;           // +3.3 MB fp32
static constexpr size_t ABF_B    = WINBUF_B + (size_t)Bb * Mq * 100 * 4; // +4.2 MB bf16
static constexpr size_t BT_B     = ABF_B + (size_t)Bb * Mq * Cc * 2;     // +4.2 MB bf16

typedef float floatx4 __attribute__((ext_vector_type(4)));
typedef short shortx8 __attribute__((ext_vector_type(8)));

union BfPack {
    shortx8 v;
    unsigned short u[8];
};

// fp32 -> bf16 round-to-nearest-even (finite inputs only)
__device__ __forceinline__ unsigned short f2bf(float f) {
    unsigned int x = __float_as_uint(f);
    x += 0x7fffu + ((x >> 16) & 1u);
    return (unsigned short)(x >> 16);
}

__device__ __forceinline__ float bf2f(unsigned short u) {
    return __uint_as_float((unsigned int)u << 16);
}

// async global->LDS, 16 B per lane; LDS dest = base + lane*16 (wave-uniform base)
__device__ __forceinline__ void gll16(const void* g, void* l) {
    __builtin_amdgcn_global_load_lds(
        (const __attribute__((address_space(1))) unsigned int*)g,
        (__attribute__((address_space(3))) unsigned int*)l, 16, 0, 0);
}

// ---------------------------------------------------------------------------
// Merged prep: blocks [0,1024) convert fmap1 fp32->bf16 (same layout);
// blocks [1024,1536) transpose fmap2 (b,c,p) -> Bt (b,p,c) bf16 via LDS tile.
// ---------------------------------------------------------------------------
__global__ __launch_bounds__(256)
void cvt_kernel(const float* __restrict__ f1, const float* __restrict__ f2,
                unsigned short* __restrict__ Abf, unsigned short* __restrict__ Bt)
{
    __shared__ float tile[64 * 65];
    const int tid = threadIdx.x;
    if (blockIdx.x < 1024) {
        const int t = blockIdx.x * 256 + tid;      // 262144 threads x 8 elems
        const float4 v0 = *(const float4*)(f1 + (size_t)t * 8);
        const float4 v1 = *(const float4*)(f1 + (size_t)t * 8 + 4);
        BfPack p;
        p.u[0] = f2bf(v0.x); p.u[1] = f2bf(v0.y);
        p.u[2] = f2bf(v0.z); p.u[3] = f2bf(v0.w);
        p.u[4] = f2bf(v1.x); p.u[5] = f2bf(v1.y);
        p.u[6] = f2bf(v1.z); p.u[7] = f2bf(v1.w);
        *(shortx8*)(Abf + (size_t)t * 8) = p.v;
        return;
    }
    const int bid = blockIdx.x - 1024;             // 512 transpose blocks
    const int p0 = (bid & 63) * 64;
    const int c0 = ((bid >> 6) & 3) * 64;
    const int b  = bid >> 8;

    // load: coalesced along p
    const int pl = tid & 63;
    const int cb = tid >> 6;     // 0..3
#pragma unroll
    for (int it = 0; it < 16; ++it) {
        const int cl = it * 4 + cb;
        tile[cl * 65 + pl] = f2[((size_t)(b * Cc + c0 + cl)) * Np + p0 + pl];
    }
    __syncthreads();

    // store: coalesced along c (8 bf16 = 16 B per thread-write)
    const int cg = (tid & 7) * 8;
#pragma unroll
    for (int it = 0; it < 2; ++it) {
        const int pw = it * 32 + (tid >> 3);
        BfPack p;
#pragma unroll
        for (int u = 0; u < 8; ++u)
            p.u[u] = f2bf(tile[(cg + u) * 65 + pw]);
        *(shortx8*)(Bt + ((size_t)(b * Np + p0 + pw)) * Cc + c0 + cg) = p.v;
    }
}

// ---------------------------------------------------------------------------
// Fused correlation GEMM + level-1 pooling + level-0 window extraction.
// Best-measured structure (R9, 120.6 us): dbuf global_load_lds K-loop with
// SOURCE-SIDE XOR BANK SWIZZLE: staging lane loads global k-group
// (lane&3)^sigma(row), sigma(row)=(row>>1)&3, so LDS slot (r,g) holds global
// (r, g^sigma(r)); fragment reads fetch slot quad^sigma(row) -> every 8-lane
// LDS phase covers all 32 banks exactly once.
// 128x128 tile, 4 waves, 4x4 16x16x32 bf16 tiles/wave, 8 K-iters.
// ---------------------------------------------------------------------------
__global__ __launch_bounds__(256)
void corr_gemm_pool_kernel(const unsigned short* __restrict__ Abf, // (Bb*Mq, Cc)
                           const unsigned short* __restrict__ Bt,  // (Bb*Np, Cc)
                           const float* __restrict__ cent,         // (Bb*Mq, 2)
                           unsigned short* __restrict__ l1buf,     // (Bb*Mq, 1024) bf16
                           float* __restrict__ winbuf)             // (Bb*Mq, 100)
{
    __shared__ union {
        unsigned short stage[2][2][128 * 32]; // [buf][a=0/b=1][row*32+k] 32 KB
        float corrT[32 * 131];                // epilogue staging (16.8 KB)
    } sm;
    __shared__ int qx0s[128], qy0s[128];

    const int b    = blockIdx.z;
    const int bm0  = blockIdx.y * 128;
    const int bx   = blockIdx.x;             // image row pair {2bx, 2bx+1}
    const int bn0  = bx * 128;
    const int tid  = threadIdx.x;
    const int lane = tid & 63;
    const int wave = tid >> 6;
    const int lane15 = lane & 15;
    const int quad   = lane >> 4;
    const int wm = (wave >> 1) * 64;
    const int wn = (wave & 1) * 64;

    if (tid < 128) {
        const float cx = cent[(size_t)(b * Mq + bm0 + tid) * 2 + 0];
        const float cy = cent[(size_t)(b * Mq + bm0 + tid) * 2 + 1];
        qx0s[tid] = (int)floorf(cx) - RAD;
        qy0s[tid] = (int)floorf(cy) - RAD;
    }

    // staging addresses: one instr covers 16 rows; lane -> row lane/4,
    // SWIZZLED k-group (lane&3)^((row>>1)&3) so slot (r,g) = global (r,g^sig)
    const int lrow = lane >> 2;
    const int lkg  = (((lane & 3) ^ ((lrow >> 1) & 3))) * 8;
    const unsigned short* aptr = Abf + (size_t)(b * Mq + bm0 + wave * 16 + lrow) * Cc + lkg;
    const unsigned short* bptr = Bt  + (size_t)(b * Np + bn0 + wave * 16 + lrow) * Cc + lkg;

    floatx4 acc[4][4];
#pragma unroll
    for (int i = 0; i < 4; ++i)
#pragma unroll
        for (int j = 0; j < 4; ++j)
            acc[i][j] = floatx4{0.0f, 0.0f, 0.0f, 0.0f};

    // prologue: stage k-tile 0 into buffer 0
    gll16(aptr,           &sm.stage[0][0][wave * 512]);
    gll16(aptr + 64 * Cc, &sm.stage[0][0][2048 + wave * 512]);
    gll16(bptr,           &sm.stage[0][1][wave * 512]);
    gll16(bptr + 64 * Cc, &sm.stage[0][1][2048 + wave * 512]);

    // reader-side swizzled k-group offset (row within 16-seg == lane15)
    const int rq = (quad ^ ((lane15 >> 1) & 3)) * 8;

    for (int k0 = 0; k0 < 8; ++k0) {
        __syncthreads();   // drains this wave's gll for buffer k0&1
        if (k0 < 7) {
            const int nb = (k0 + 1) & 1;
            const int ko = (k0 + 1) * 32;
            gll16(aptr + ko,           &sm.stage[nb][0][wave * 512]);
            gll16(aptr + 64 * Cc + ko, &sm.stage[nb][0][2048 + wave * 512]);
            gll16(bptr + ko,           &sm.stage[nb][1][wave * 512]);
            gll16(bptr + 64 * Cc + ko, &sm.stage[nb][1][2048 + wave * 512]);
        }
        const unsigned short* la = sm.stage[k0 & 1][0];
        const unsigned short* lb = sm.stage[k0 & 1][1];
        shortx8 af[4], bf[4];
#pragma unroll
        for (int i = 0; i < 4; ++i)
            af[i] = *(const shortx8*)&la[(wm + i * 16 + lane15) * 32 + rq];
#pragma unroll
        for (int j = 0; j < 4; ++j)
            bf[j] = *(const shortx8*)&lb[(wn + j * 16 + lane15) * 32 + rq];
#pragma unroll
        for (int i = 0; i < 4; ++i)
#pragma unroll
            for (int j = 0; j < 4; ++j)
                acc[i][j] = __builtin_amdgcn_mfma_f32_16x16x32_bf16(
                    af[i], bf[j], acc[i][j], 0, 0, 0);
    }

    // ---- epilogue: 4 chunks of 32 queries through LDS; pool + window ----
    // C/D layout: col = lane15, row = quad*4+reg (m89/m91 verified).
    float* corrT = sm.corrT;
    const int m_local = tid >> 3;   // 0..31 (query within chunk)
    const int xi      = tid & 7;
#pragma unroll
    for (int c = 0; c < 4; ++c) {
        __syncthreads();
        if ((wave >> 1) == (c >> 1)) {
#pragma unroll
            for (int ii = 0; ii < 2; ++ii) {
                const int i = 2 * (c & 1) + ii;
#pragma unroll
                for (int j = 0; j < 4; ++j) {
#pragma unroll
                    for (int reg = 0; reg < 4; ++reg) {
                        const int rl = ii * 16 + quad * 4 + reg;
                        const int n  = wn + j * 16 + lane15;
                        corrT[rl * 131 + n] = acc[i][j][reg];
                    }
                }
            }
        }
        __syncthreads();

        const int mg = 32 * c + m_local;            // block-local query
        const size_t gq = (size_t)(b * Mq + bm0 + mg);
        const float* T = &corrT[m_local * 131];

        // 2x2 pool -> one L1 row (32 bf16 values) per query
#pragma unroll
        for (int k = 0; k < 4; ++k) {
            const int c1 = xi + 8 * k;
            const float v = 0.25f * (T[2 * c1] + T[2 * c1 + 1]
                                   + T[64 + 2 * c1] + T[64 + 2 * c1 + 1]);
            l1buf[gq * 1024 + bx * 32 + c1] = f2bf(v);
        }

        // level-0 window rows intersecting [qy0, qy0+9] (fp32, exact)
        const int x0w = qx0s[mg];
        const int y0w = qy0s[mg];
#pragma unroll
        for (int par = 0; par < 2; ++par) {
            const int wy = 2 * bx + par - y0w;
            if (wy >= 0 && wy < 10) {
#pragma unroll
                for (int t = 0; t < 2; ++t) {
                    const int wx = xi + t * 8;
                    if (wx < 10) {
                        const int x = x0w + wx;
                        if (x >= 0 && x < Ww)
                            winbuf[gq * 100 + wy * 10 + wx] = T[par * 64 + x];
                    }
                }
            }
        }
    }
}

// ---------------------------------------------------------------------------
// Sampler: 8 queries/block. Loads L1 (2 KB bf16/query) + window (400 B/query),
// builds L2/L3 in LDS, emits all 324 outputs per query.
// ---------------------------------------------------------------------------
__global__ __launch_bounds__(256)
void pyr_sample_kernel(const float* __restrict__ cent,           // (Bb*Mq, 2)
                       const unsigned short* __restrict__ l1buf, // (Bb*Mq, 1024) bf16
                       const float* __restrict__ winbuf,         // (Bb*Mq, 100)
                       float* __restrict__ out)                  // (Bb, 324, Mq)
{
    __shared__ float l1[8][1024];    // 32x32
    __shared__ float l2[8][256];     // 16x16
    __shared__ float l3[8][64];      // 8x8
    __shared__ float win0[8][100];   // 10x10 L0 window
    __shared__ float qcx[8], qcy[8];
    __shared__ int   qx0[8], qy0[8];

    const int tid = threadIdx.x;
    const int b   = blockIdx.x >> 9;           // 512 blocks per batch
    const int m0  = (blockIdx.x & 511) * 8;
    const size_t gq0 = (size_t)(b * Mq + m0);

    if (tid < 8) {
        const float cx = cent[(gq0 + tid) * 2 + 0];
        const float cy = cent[(gq0 + tid) * 2 + 1];
        qcx[tid] = cx; qcy[tid] = cy;
        qx0[tid] = (int)floorf(cx) - RAD;
        qy0[tid] = (int)floorf(cy) - RAD;
    }

    // load L1: 8 queries x 128 ushort8 (16 B) each -> expand bf16 to f32 LDS
#pragma unroll
    for (int it = 0; it < 4; ++it) {
        const int v = it * 256 + tid;          // ushort8 index, 0..1023
        const int q = v >> 7;
        const int o = v & 127;
        BfPack p;
        p.v = *(const shortx8*)&l1buf[(gq0 + q) * 1024 + o * 8];
#pragma unroll
        for (int u = 0; u < 8; ++u)
            l1[q][o * 8 + u] = bf2f(p.u[u]);
    }
    // load windows: 8 queries x 25 float4
    if (tid < 200) {
        const int q = tid / 25;
        const int o = tid - q * 25;
        *(float4*)&win0[q][o * 4] = *(const float4*)&winbuf[(gq0 + q) * 100 + o * 4];
    }
    __syncthreads();

    // L2 from L1
#pragma unroll
    for (int i = 0; i < 8; ++i) {
        const int idx = i * 256 + tid;
        const int q = idx >> 8;
        const int c = idx & 255;
        const int cy2 = c >> 4, cx2 = c & 15;
        const float* s = &l1[q][(2 * cy2) * 32 + 2 * cx2];
        l2[q][c] = 0.25f * (s[0] + s[1] + s[32] + s[33]);
    }
    __syncthreads();
    // L3 from L2
#pragma unroll
    for (int i = 0; i < 2; ++i) {
        const int idx = i * 256 + tid;
        const int q = idx >> 6;
        const int c = idx & 63;
        const int cy3 = c >> 3, cx3 = c & 7;
        const float* s = &l2[q][(2 * cy3) * 16 + 2 * cx3];
        l3[q][c] = 0.25f * (s[0] + s[1] + s[16] + s[17]);
    }
    __syncthreads();

    // sampling: 324*8 = 2592 outputs
    for (int i = 0; i < 11; ++i) {
        const int idx = i * 256 + tid;
        if (idx >= KTOT * 8) break;
        const int q  = idx & 7;
        const int kk = idx >> 3;           // 0..323
        const int lvl = kk / KPL;
        const int r   = kk - lvl * KPL;
        const int di  = r / SIDE;          // x-offset index
        const int dj  = r - di * SIDE;     // y-offset index

        const int w = Ww >> lvl;
        const float scale = 1.0f / (float)(1 << lvl);
        const float x = qcx[q] * scale + (float)(di - RAD);
        const float y = qcy[q] * scale + (float)(dj - RAD);

        const float x0f = floorf(x), y0f = floorf(y);
        const float wx1 = x - x0f, wx0 = 1.0f - wx1;
        const float wy1 = y - y0f, wy0 = 1.0f - wy1;
        const float fmx = (float)(w - 1);
        const bool vx0 = (x0f >= 0.0f) && (x0f <= fmx);
        const bool vx1 = (x0f + 1.0f >= 0.0f) && (x0f + 1.0f <= fmx);
        const bool vy0 = (y0f >= 0.0f) && (y0f <= fmx);
        const bool vy1 = (y0f + 1.0f >= 0.0f) && (y0f + 1.0f <= fmx);

        const int ix0 = (int)x0f, iy0 = (int)y0f;

        const float* buf;
        int stride, ox, oy;
        if (lvl == 0)      { buf = win0[q]; stride = 10; ox = qx0[q]; oy = qy0[q]; }
        else if (lvl == 1) { buf = l1[q];   stride = 32; ox = 0; oy = 0; }
        else if (lvl == 2) { buf = l2[q];   stride = 16; ox = 0; oy = 0; }
        else               { buf = l3[q];   stride =  8; ox = 0; oy = 0; }

        const int cx0 = ix0 - ox, cx1 = ix0 + 1 - ox;
        const int cy0r = iy0 - oy, cy1r = iy0 + 1 - oy;
        const float g00 = (vx0 && vy0) ? buf[cy0r * stride + cx0] : 0.0f;
        const float g10 = (vx1 && vy0) ? buf[cy0r * stride + cx1] : 0.0f;
        const float g01 = (vx0 && vy1) ? buf[cy1r * stride + cx0] : 0.0f;
        const float g11 = (vx1 && vy1) ? buf[cy1r * stride + cx1] : 0.0f;

        out[((size_t)b * KTOT + kk) * Mq + m0 + q] =
            wy0 * (wx0 * g00 + wx1 * g10) + wy1 * (wx0 * g01 + wx1 * g11);
    }
}

extern "C" void kernel_launch(void* const* d_in, const int* in_sizes, int n_in,
                              void* d_out, int out_size, void* d_ws, size_t ws_size,
                              hipStream_t stream)
{
    const float* fmap1 = (const float*)d_in[0];   // (Bb, Mq, Cc)
    const float* fmap2 = (const float*)d_in[1];   // (Bb, Cc, Hh, Ww)
    const float* cent  = (const float*)d_in[2];   // (Bb, Mq, 2)
    char* ws = (char*)d_ws;
    unsigned short* l1buf = (unsigned short*)(ws + L1BUF_B);
    float* winbuf = (float*)(ws + WINBUF_B);
    unsigned short* Abf = (unsigned short*)(ws + ABF_B);
    unsigned short* Bt  = (unsigned short*)(ws + BT_B);
    float* out = (float*)d_out;

    // 0) merged prep: A cvt (1024 blocks) + B transpose/cvt (512 blocks)
    cvt_kernel<<<1536, 256, 0, stream>>>(fmap1, fmap2, Abf, Bt);

    // 1) fused correlation GEMM (dbuf global_load_lds, bank-swizzled LDS)
    //    + L1 pooling (bf16 out) + L0 window extraction
    dim3 ggrid(Np / 128, Mq / 128, Bb);
    corr_gemm_pool_kernel<<<ggrid, 256, 0, stream>>>(Abf, Bt, cent, l1buf, winbuf);

    // 2) pyramid completion (L2/L3 in LDS) + bilinear sampling
    const int nblk = Bb * Mq / 8;   // 1024
    pyr_sample_kernel<<<nblk, 256, 0, stream>>>(cent, l1buf, winbuf, out);
}